// Round 1
// baseline (2243.945 us; speedup 1.0000x reference)
//
#include <hip/hip_runtime.h>
#include <hip/hip_bf16.h>
#include <math.h>

#define NTOK 8192
#define DIM  1024

typedef __attribute__((ext_vector_type(8))) short          short8;
typedef __attribute__((ext_vector_type(4))) float          f32x4;
typedef __attribute__((ext_vector_type(4))) unsigned short us4;

static __device__ __forceinline__ unsigned short f2b(float f) {
    unsigned int u = __builtin_bit_cast(unsigned int, f);
    u += 0x7FFFu + ((u >> 16) & 1u);   // RNE round to bf16
    return (unsigned short)(u >> 16);
}
static __device__ __forceinline__ float b2f(unsigned short s) {
    unsigned int u = ((unsigned int)s) << 16;
    return __builtin_bit_cast(float, u);
}
static __device__ __forceinline__ short8 cvt8(f32x4 a, f32x4 b) {
    short8 r;
    r[0] = (short)f2b(a[0]); r[1] = (short)f2b(a[1]);
    r[2] = (short)f2b(a[2]); r[3] = (short)f2b(a[3]);
    r[4] = (short)f2b(b[0]); r[5] = (short)f2b(b[1]);
    r[6] = (short)f2b(b[2]); r[7] = (short)f2b(b[3]);
    return r;
}

// ---------------- gating: logits -> top2 -> renorm -> per-expert lists ----
__global__ __launch_bounds__(256) void gating_kernel(
    const float* __restrict__ x, const float* __restrict__ Wg,
    int* __restrict__ cnt, int* __restrict__ toks, float* __restrict__ wl)
{
    const int tok  = blockIdx.x * 4 + (threadIdx.x >> 6);
    const int lane = threadIdx.x & 63;
    const float4* xr = (const float4*)(x + (size_t)tok * DIM);
    float4 xv[4];
    #pragma unroll
    for (int j = 0; j < 4; ++j) xv[j] = xr[lane + j * 64];
    float lg[8];
    #pragma unroll
    for (int e = 0; e < 8; ++e) {
        const float4* wr = (const float4*)(Wg + e * DIM);
        float s = 0.f;
        #pragma unroll
        for (int j = 0; j < 4; ++j) {
            float4 wv = wr[lane + j * 64];
            s += xv[j].x * wv.x + xv[j].y * wv.y + xv[j].z * wv.z + xv[j].w * wv.w;
        }
        #pragma unroll
        for (int o = 32; o > 0; o >>= 1) s += __shfl_xor(s, o);
        lg[e] = s;
    }
    int i1 = 0; float m1 = lg[0];
    #pragma unroll
    for (int e = 1; e < 8; ++e) if (lg[e] > m1) { m1 = lg[e]; i1 = e; }
    int i2 = -1; float m2 = -3.4e38f;
    #pragma unroll
    for (int e = 0; e < 8; ++e) if (e != i1 && lg[e] > m2) { m2 = lg[e]; i2 = e; }
    // renormalized top-2 weights: p1/(p1+p2) = 1/(1+e^(l2-l1))
    const float e2 = expf(m2 - m1);
    const float wa = 1.f / (1.f + e2);
    const float wb = 1.f - wa;
    if (lane == 0) {
        int s1 = atomicAdd(&cnt[i1], 1);
        toks[i1 * NTOK + s1] = tok; wl[i1 * NTOK + s1] = wa;
        int s2 = atomicAdd(&cnt[i2], 1);
        toks[i2 * NTOK + s2] = tok; wl[i2 * NTOK + s2] = wb;
    }
}

// ---------------- RMS norm + bf16 casts ----------------------------------
__global__ __launch_bounds__(256) void normcvt_kernel(
    const float* __restrict__ x,
    unsigned short* __restrict__ yb, unsigned short* __restrict__ xb)
{
    const int tok  = blockIdx.x * 4 + (threadIdx.x >> 6);
    const int lane = threadIdx.x & 63;
    const float4* xr = (const float4*)(x + (size_t)tok * DIM);
    float4 xv[4];
    float ss = 0.f;
    #pragma unroll
    for (int j = 0; j < 4; ++j) {
        xv[j] = xr[lane + j * 64];
        ss += xv[j].x * xv[j].x + xv[j].y * xv[j].y + xv[j].z * xv[j].z + xv[j].w * xv[j].w;
    }
    #pragma unroll
    for (int o = 32; o > 0; o >>= 1) ss += __shfl_xor(ss, o);
    const float rinv = 1.f / sqrtf(ss * (1.f / (float)DIM) + 1e-6f);
    us4* yo = (us4*)(yb + (size_t)tok * DIM);
    us4* xo = (us4*)(xb + (size_t)tok * DIM);
    #pragma unroll
    for (int j = 0; j < 4; ++j) {
        us4 yv, xv4;
        yv[0] = f2b(xv[j].x * rinv); yv[1] = f2b(xv[j].y * rinv);
        yv[2] = f2b(xv[j].z * rinv); yv[3] = f2b(xv[j].w * rinv);
        xv4[0] = f2b(xv[j].x); xv4[1] = f2b(xv[j].y);
        xv4[2] = f2b(xv[j].z); xv4[3] = f2b(xv[j].w);
        yo[lane + j * 64] = yv;
        xo[lane + j * 64] = xv4;
    }
}

// ---------------- GEMM1: h = silu(A W1^T) * (A W3^T)  (A gathered) --------
// A: [cnt, DIM] bf16 rows gathered via toks; W1/W3: [HDIM, DIM] fp32 (K contig)
// rms_w folded into W1/W3 columns at stage time (fractal only).
template<int HDIM, bool FRAC>
__global__ __launch_bounds__(256, 2) void gemm1_kernel(
    const unsigned short* __restrict__ Asrc,
    const float* __restrict__ W1, const float* __restrict__ W3,
    const float* __restrict__ rms,
    const int* __restrict__ cntp, const int* __restrict__ toks,
    unsigned short* __restrict__ h)
{
    const int c  = *cntp;
    const int m0 = blockIdx.x * 128;
    if (m0 >= c) return;
    const int n0 = blockIdx.y * 128;

    __shared__ unsigned short As[128][56];   // pad 32->56 (16B-aligned rows, ~2-way banks)
    __shared__ unsigned short B1s[128][56];
    __shared__ unsigned short B3s[128][56];

    const int t    = threadIdx.x;
    const int lane = t & 63;
    const int wv   = t >> 6;
    const int wr   = (wv >> 1) * 64;
    const int wc   = (wv & 1) * 64;
    const int fr   = lane & 15;
    const int fq   = lane >> 4;

    const int srow = t >> 1;          // staging row 0..127
    const int scol = (t & 1) * 16;    // staging col 0 or 16 (of BK=32)
    const int gr   = m0 + srow;
    const int atok = (gr < c) ? toks[gr] : 0;
    const unsigned short* aptr = Asrc + (size_t)atok * DIM + scol;
    const float* w1ptr = W1 + (size_t)(n0 + srow) * DIM + scol;
    const float* w3ptr = W3 + (size_t)(n0 + srow) * DIM + scol;

    f32x4 accU[4][4] = {};
    f32x4 accV[4][4] = {};

    for (int k0 = 0; k0 < DIM; k0 += 32) {
        short8 a0 = *(const short8*)(aptr + k0);
        short8 a1 = *(const short8*)(aptr + k0 + 8);
        f32x4 u0 = *(const f32x4*)(w1ptr + k0);
        f32x4 u1 = *(const f32x4*)(w1ptr + k0 + 4);
        f32x4 u2 = *(const f32x4*)(w1ptr + k0 + 8);
        f32x4 u3 = *(const f32x4*)(w1ptr + k0 + 12);
        f32x4 v0 = *(const f32x4*)(w3ptr + k0);
        f32x4 v1 = *(const f32x4*)(w3ptr + k0 + 4);
        f32x4 v2 = *(const f32x4*)(w3ptr + k0 + 8);
        f32x4 v3 = *(const f32x4*)(w3ptr + k0 + 12);
        if constexpr (FRAC) {
            f32x4 r0 = *(const f32x4*)(rms + scol + k0);
            f32x4 r1 = *(const f32x4*)(rms + scol + k0 + 4);
            f32x4 r2 = *(const f32x4*)(rms + scol + k0 + 8);
            f32x4 r3 = *(const f32x4*)(rms + scol + k0 + 12);
            u0 *= r0; u1 *= r1; u2 *= r2; u3 *= r3;
            v0 *= r0; v1 *= r1; v2 *= r2; v3 *= r3;
        }
        short8 b1lo = cvt8(u0, u1), b1hi = cvt8(u2, u3);
        short8 b3lo = cvt8(v0, v1), b3hi = cvt8(v2, v3);
        __syncthreads();
        *(short8*)&As[srow][scol]      = a0;
        *(short8*)&As[srow][scol + 8]  = a1;
        *(short8*)&B1s[srow][scol]     = b1lo;
        *(short8*)&B1s[srow][scol + 8] = b1hi;
        *(short8*)&B3s[srow][scol]     = b3lo;
        *(short8*)&B3s[srow][scol + 8] = b3hi;
        __syncthreads();

        short8 af[4], b1f[4], b3f[4];
        #pragma unroll
        for (int i = 0; i < 4; ++i) {
            af[i]  = *(const short8*)&As [wr + i * 16 + fr][fq * 8];
            b1f[i] = *(const short8*)&B1s[wc + i * 16 + fr][fq * 8];
            b3f[i] = *(const short8*)&B3s[wc + i * 16 + fr][fq * 8];
        }
        #pragma unroll
        for (int mi = 0; mi < 4; ++mi) {
            #pragma unroll
            for (int ni = 0; ni < 4; ++ni) {
                accU[mi][ni] = __builtin_amdgcn_mfma_f32_16x16x32_bf16(af[mi], b1f[ni], accU[mi][ni], 0, 0, 0);
                accV[mi][ni] = __builtin_amdgcn_mfma_f32_16x16x32_bf16(af[mi], b3f[ni], accV[mi][ni], 0, 0, 0);
            }
        }
    }

    #pragma unroll
    for (int mi = 0; mi < 4; ++mi) {
        #pragma unroll
        for (int ni = 0; ni < 4; ++ni) {
            #pragma unroll
            for (int r = 0; r < 4; ++r) {
                const int slot = m0 + wr + mi * 16 + fq * 4 + r;
                if (slot < c) {
                    const int hcol = n0 + wc + ni * 16 + fr;
                    const float uu = accU[mi][ni][r];
                    const float vv = accV[mi][ni][r];
                    const float hv = uu / (1.f + __expf(-uu)) * vv;
                    h[(size_t)slot * HDIM + hcol] = f2b(hv);
                }
            }
        }
    }
}

// ---------------- GEMM2: s = h W2^T; scatter-add weighted epilogue --------
template<int K, bool FRAC>
__global__ __launch_bounds__(256, 2) void gemm2_kernel(
    const unsigned short* __restrict__ hsrc,
    const float* __restrict__ W2,
    const int* __restrict__ cntp, const int* __restrict__ toks,
    const float* __restrict__ wl,
    const float* __restrict__ x, const unsigned short* __restrict__ yb,
    const float* __restrict__ rms, const float* __restrict__ gam,
    float* __restrict__ out)
{
    const int c  = *cntp;
    const int m0 = blockIdx.x * 128;
    if (m0 >= c) return;
    const int n0 = blockIdx.y * 128;

    __shared__ unsigned short As[128][56];
    __shared__ unsigned short Bs[128][56];

    const int t    = threadIdx.x;
    const int lane = t & 63;
    const int wv   = t >> 6;
    const int wr   = (wv >> 1) * 64;
    const int wc   = (wv & 1) * 64;
    const int fr   = lane & 15;
    const int fq   = lane >> 4;

    const int srow = t >> 1;
    const int scol = (t & 1) * 16;
    const unsigned short* aptr = hsrc + (size_t)(m0 + srow) * K + scol;
    const float* w2ptr = W2 + (size_t)(n0 + srow) * K + scol;

    f32x4 acc[4][4] = {};

    for (int k0 = 0; k0 < K; k0 += 32) {
        short8 a0 = *(const short8*)(aptr + k0);
        short8 a1 = *(const short8*)(aptr + k0 + 8);
        f32x4 u0 = *(const f32x4*)(w2ptr + k0);
        f32x4 u1 = *(const f32x4*)(w2ptr + k0 + 4);
        f32x4 u2 = *(const f32x4*)(w2ptr + k0 + 8);
        f32x4 u3 = *(const f32x4*)(w2ptr + k0 + 12);
        short8 blo = cvt8(u0, u1), bhi = cvt8(u2, u3);
        __syncthreads();
        *(short8*)&As[srow][scol]     = a0;
        *(short8*)&As[srow][scol + 8] = a1;
        *(short8*)&Bs[srow][scol]     = blo;
        *(short8*)&Bs[srow][scol + 8] = bhi;
        __syncthreads();

        short8 af[4], bf[4];
        #pragma unroll
        for (int i = 0; i < 4; ++i) {
            af[i] = *(const short8*)&As[wr + i * 16 + fr][fq * 8];
            bf[i] = *(const short8*)&Bs[wc + i * 16 + fr][fq * 8];
        }
        #pragma unroll
        for (int mi = 0; mi < 4; ++mi) {
            #pragma unroll
            for (int ni = 0; ni < 4; ++ni)
                acc[mi][ni] = __builtin_amdgcn_mfma_f32_16x16x32_bf16(af[mi], bf[ni], acc[mi][ni], 0, 0, 0);
        }
    }

    #pragma unroll
    for (int mi = 0; mi < 4; ++mi) {
        #pragma unroll
        for (int ni = 0; ni < 4; ++ni) {
            #pragma unroll
            for (int r = 0; r < 4; ++r) {
                const int slot = m0 + wr + mi * 16 + fq * 4 + r;
                if (slot < c) {
                    const int tok  = toks[slot];
                    const float wt = wl[slot];
                    const int dcol = n0 + wc + ni * 16 + fr;
                    const float s  = acc[mi][ni][r];
                    float val;
                    if constexpr (FRAC) {
                        const float yv = b2f(yb[(size_t)tok * DIM + dcol]) * rms[dcol];
                        val = gam[dcol] * (yv + s) + x[(size_t)tok * DIM + dcol];
                    } else {
                        val = s;
                    }
                    out[(size_t)tok * DIM + dcol] += wt * val;
                }
            }
        }
    }
}

// --------------------------------------------------------------------------
extern "C" void kernel_launch(void* const* d_in, const int* in_sizes, int n_in,
                              void* d_out, int out_size, void* d_ws, size_t ws_size,
                              hipStream_t stream)
{
    const float* x    = (const float*)d_in[0];
    const float* Wg   = (const float*)d_in[1];
    const float* rmsw = (const float*)d_in[2];
    const float* gam  = (const float*)d_in[3];
    const float* w1f  = (const float*)d_in[4];
    const float* w3f  = (const float*)d_in[5];
    const float* w2f  = (const float*)d_in[6];
    const float* w1p  = (const float*)d_in[7];
    const float* w3p  = (const float*)d_in[8];
    const float* w2p  = (const float*)d_in[9];
    float* out = (float*)d_out;

    // workspace layout (needs ~97 MiB)
    char* ws = (char*)d_ws;
    int*   cnt  = (int*)ws;                               // 8 ints (zeroed)
    int*   toks = (int*)(ws + 256);                       // [8][8192]
    float* wl   = (float*)(ws + 256 + 8 * NTOK * 4);      // [8][8192]
    unsigned short* yb = (unsigned short*)(ws + (1 << 20));          // [8192][1024] bf16
    unsigned short* xb = yb + (size_t)NTOK * DIM;                    // [8192][1024] bf16
    unsigned short* h  = xb + (size_t)NTOK * DIM;                    // [8192][4096] bf16 max

    hipMemsetAsync(cnt, 0, 256, stream);
    hipMemsetAsync(out, 0, (size_t)out_size * sizeof(float), stream);

    gating_kernel <<<NTOK / 4, 256, 0, stream>>>(x, Wg, cnt, toks, wl);
    normcvt_kernel<<<NTOK / 4, 256, 0, stream>>>(x, yb, xb);

    for (int f = 0; f < 4; ++f) {
        const int e = f;
        gemm1_kernel<2048, true><<<dim3(64, 16), 256, 0, stream>>>(
            yb, w1f + (size_t)f * 2048 * DIM, w3f + (size_t)f * 2048 * DIM,
            rmsw + (size_t)f * DIM, cnt + e, toks + (size_t)e * NTOK, h);
        gemm2_kernel<2048, true><<<dim3(64, 8), 256, 0, stream>>>(
            h, w2f + (size_t)f * DIM * 2048, cnt + e, toks + (size_t)e * NTOK,
            wl + (size_t)e * NTOK, x, yb, rmsw + (size_t)f * DIM, gam + (size_t)f * DIM, out);
    }
    for (int p = 0; p < 4; ++p) {
        const int e = 4 + p;
        gemm1_kernel<4096, false><<<dim3(64, 32), 256, 0, stream>>>(
            xb, w1p + (size_t)p * 4096 * DIM, w3p + (size_t)p * 4096 * DIM,
            nullptr, cnt + e, toks + (size_t)e * NTOK, h);
        gemm2_kernel<4096, false><<<dim3(64, 8), 256, 0, stream>>>(
            h, w2p + (size_t)p * DIM * 4096, cnt + e, toks + (size_t)e * NTOK,
            wl + (size_t)e * NTOK, nullptr, nullptr, nullptr, nullptr, out);
    }
}

// Round 2
// 701.256 us; speedup vs baseline: 3.1999x; 3.1999x over previous
//
#include <hip/hip_runtime.h>
#include <hip/hip_bf16.h>
#include <math.h>

#define NTOK 8192
#define DIM  1024

typedef __attribute__((ext_vector_type(8))) short          short8;
typedef __attribute__((ext_vector_type(4))) float          f32x4;
typedef __attribute__((ext_vector_type(4))) unsigned short us4;

static __device__ __forceinline__ unsigned short f2b(float f) {
    unsigned int u = __builtin_bit_cast(unsigned int, f);
    u += 0x7FFFu + ((u >> 16) & 1u);   // RNE round to bf16
    return (unsigned short)(u >> 16);
}
static __device__ __forceinline__ float b2f(unsigned short s) {
    unsigned int u = ((unsigned int)s) << 16;
    return __builtin_bit_cast(float, u);
}
static __device__ __forceinline__ short8 cvt8(f32x4 a, f32x4 b) {
    short8 r;
    r[0] = (short)f2b(a[0]); r[1] = (short)f2b(a[1]);
    r[2] = (short)f2b(a[2]); r[3] = (short)f2b(a[3]);
    r[4] = (short)f2b(b[0]); r[5] = (short)f2b(b[1]);
    r[6] = (short)f2b(b[2]); r[7] = (short)f2b(b[3]);
    return r;
}
static __device__ __forceinline__ void gload16(const unsigned short* g, unsigned short* l) {
    __builtin_amdgcn_global_load_lds(
        (const __attribute__((address_space(1))) void*)g,
        (__attribute__((address_space(3))) void*)l, 16, 0, 0);
}

// bf16 weight-pool element offsets (compile-time layout)
#define W1F_OFF 0u
#define W3F_OFF 8388608u
#define W2F_OFF 16777216u
#define W1P_OFF 25165824u
#define W3P_OFF 41943040u
#define W2P_OFF 58720256u
#define WTOT    75497472u

// ctrl layout (ints): [0..7]=cnt, [8]=g1n, [9]=g2n, [10..17]=hbase (element offs)

// ---------------- gating + RMS norm + bf16 casts (no atomics) -------------
__global__ __launch_bounds__(256) void gate_norm(
    const float* __restrict__ x, const float* __restrict__ Wg,
    int* __restrict__ sel, float* __restrict__ wt,
    unsigned short* __restrict__ yb, unsigned short* __restrict__ xb)
{
    const int tok  = blockIdx.x * 4 + (threadIdx.x >> 6);
    const int lane = threadIdx.x & 63;
    const float4* xr = (const float4*)(x + (size_t)tok * DIM);
    float4 xv[4];
    float ss = 0.f;
    #pragma unroll
    for (int j = 0; j < 4; ++j) {
        xv[j] = xr[lane + j * 64];
        ss += xv[j].x * xv[j].x + xv[j].y * xv[j].y + xv[j].z * xv[j].z + xv[j].w * xv[j].w;
    }
    float lg[8];
    #pragma unroll
    for (int e = 0; e < 8; ++e) {
        const float4* wr = (const float4*)(Wg + e * DIM);
        float s = 0.f;
        #pragma unroll
        for (int j = 0; j < 4; ++j) {
            float4 wv = wr[lane + j * 64];
            s += xv[j].x * wv.x + xv[j].y * wv.y + xv[j].z * wv.z + xv[j].w * wv.w;
        }
        #pragma unroll
        for (int o = 32; o > 0; o >>= 1) s += __shfl_xor(s, o);
        lg[e] = s;
    }
    #pragma unroll
    for (int o = 32; o > 0; o >>= 1) ss += __shfl_xor(ss, o);

    int i1 = 0; float m1 = lg[0];
    #pragma unroll
    for (int e = 1; e < 8; ++e) if (lg[e] > m1) { m1 = lg[e]; i1 = e; }
    int i2 = -1; float m2 = -3.4e38f;
    #pragma unroll
    for (int e = 0; e < 8; ++e) if (e != i1 && lg[e] > m2) { m2 = lg[e]; i2 = e; }
    const float wa = 1.f / (1.f + expf(m2 - m1));
    if (lane == 0) { sel[tok] = i1 | (i2 << 4); wt[tok] = wa; }

    const float rinv = 1.f / sqrtf(ss * (1.f / (float)DIM) + 1e-6f);
    us4* yo = (us4*)(yb + (size_t)tok * DIM);
    us4* xo = (us4*)(xb + (size_t)tok * DIM);
    #pragma unroll
    for (int j = 0; j < 4; ++j) {
        us4 yv, xv4;
        yv[0] = f2b(xv[j].x * rinv); yv[1] = f2b(xv[j].y * rinv);
        yv[2] = f2b(xv[j].z * rinv); yv[3] = f2b(xv[j].w * rinv);
        xv4[0] = f2b(xv[j].x); xv4[1] = f2b(xv[j].y);
        xv4[2] = f2b(xv[j].z); xv4[3] = f2b(xv[j].w);
        yo[lane + j * 64] = yv;
        xo[lane + j * 64] = xv4;
    }
}

// ---------------- per-expert list build: deterministic block scan ---------
__global__ __launch_bounds__(256) void build_lists(
    const int* __restrict__ sel, const float* __restrict__ wt,
    int* __restrict__ toks, float* __restrict__ wl, int* __restrict__ ctrl)
{
    const int e    = blockIdx.x;
    const int tid  = threadIdx.x;
    const int lane = tid & 63;
    const int wv   = tid >> 6;
    __shared__ int wbase[4];
    __shared__ int running;
    if (tid == 0) running = 0;
    __syncthreads();
    for (int c0 = 0; c0 < NTOK; c0 += 256) {
        const int tok = c0 + tid;
        const int s   = sel[tok];
        const int e1  = s & 15, e2 = s >> 4;
        const bool m  = (e1 == e) || (e2 == e);
        const float w = (e1 == e) ? wt[tok] : 1.f - wt[tok];
        const unsigned long long b = __ballot(m);
        const int pre  = __popcll(b & ((1ull << lane) - 1ull));
        const int wtot = __popcll(b);
        if (lane == 0) wbase[wv] = wtot;
        __syncthreads();
        int off = running;
        for (int j = 0; j < 4; ++j) if (j < wv) off += wbase[j];
        if (m) { toks[e * NTOK + off + pre] = tok; wl[e * NTOK + off + pre] = w; }
        __syncthreads();
        if (tid == 0) running += wbase[0] + wbase[1] + wbase[2] + wbase[3];
        __syncthreads();
    }
    if (tid == 0) ctrl[e] = running;
}

// ---------------- weight fp32 -> bf16 pool (rms folded into w1f/w3f) -----
__global__ __launch_bounds__(256) void cvtw_kernel(
    const float* __restrict__ w1f, const float* __restrict__ w3f, const float* __restrict__ w2f,
    const float* __restrict__ w1p, const float* __restrict__ w3p, const float* __restrict__ w2p,
    const float* __restrict__ rmsw, unsigned short* __restrict__ wpool)
{
    const long long NV = (long long)WTOT / 8;
    for (long long v = (long long)blockIdx.x * 256 + threadIdx.x; v < NV;
         v += (long long)gridDim.x * 256) {
        const long long eb = v << 3;
        const float* src; long long rel; bool foldr = false;
        if (eb < (long long)W3F_OFF)      { src = w1f; rel = eb;                       foldr = true; }
        else if (eb < (long long)W2F_OFF) { src = w3f; rel = eb - (long long)W3F_OFF;  foldr = true; }
        else if (eb < (long long)W1P_OFF) { src = w2f; rel = eb - (long long)W2F_OFF; }
        else if (eb < (long long)W3P_OFF) { src = w1p; rel = eb - (long long)W1P_OFF; }
        else if (eb < (long long)W2P_OFF) { src = w3p; rel = eb - (long long)W3P_OFF; }
        else                              { src = w2p; rel = eb - (long long)W2P_OFF; }
        f32x4 a = *(const f32x4*)(src + rel);
        f32x4 b = *(const f32x4*)(src + rel + 4);
        if (foldr) {
            const int f = (int)(rel >> 21);
            const int d = (int)(rel & 1023);
            a *= *(const f32x4*)(rmsw + f * 1024 + d);
            b *= *(const f32x4*)(rmsw + f * 1024 + d + 4);
        }
        *(short8*)(wpool + eb) = cvt8(a, b);
    }
}

// ---------------- device tile tables + h-pool offsets ---------------------
__global__ __launch_bounds__(256) void make_tiles(
    int* __restrict__ ctrl, int* __restrict__ g1tab, int* __restrict__ g2tab, int mode)
{
    __shared__ int mt[8];
    const int tid = threadIdx.x;
    if (tid < 8) mt[tid] = (ctrl[tid] + 127) >> 7;
    __syncthreads();
    const int ehi = (mode == 0) ? 8 : 4;
    if (tid == 0) {
        long long hb = 0;
        for (int e = 0; e < 8; ++e) {
            if (e < ehi) { ctrl[10 + e] = (int)hb; hb += (long long)mt[e] * 128 * (e < 4 ? 2048 : 4096); }
            else ctrl[10 + e] = 0;
        }
    }
    int base = 0;
    for (int e = 0; e < ehi; ++e) {
        const int nt = (e < 4) ? 16 : 32;
        const int ct = mt[e] * nt;
        for (int i = tid; i < ct; i += 256)
            g1tab[base + i] = e | ((i / nt) << 4) | ((i % nt) << 12);
        base += ct;
    }
    if (tid == 0) ctrl[8] = base;
    base = 0;
    for (int e = 0; e < ehi; ++e) {
        const int ct = mt[e] * 8;
        for (int i = tid; i < ct; i += 256)
            g2tab[base + i] = e | ((i >> 3) << 4) | ((i & 7) << 12);
        base += ct;
    }
    if (tid == 0) ctrl[9] = base;
}

// ---------------- GEMM1 (bf16 weights, global_load_lds, XOR swizzle) -----
// h[slot, 0:HD] = silu(A W1^T) * (A W3^T), A rows gathered by toks.
template<bool TAB>
__global__ __launch_bounds__(256, 2) void g1_bf16(
    const int* __restrict__ ctrl, const int* __restrict__ g1tab,
    const unsigned short* __restrict__ yb, const unsigned short* __restrict__ xb,
    const unsigned short* __restrict__ wpool,
    const int* __restrict__ toks, unsigned short* __restrict__ hpool, int e_fixed)
{
    int e, m0, n0;
    if constexpr (TAB) {
        const int t = blockIdx.x;
        if (t >= ctrl[8]) return;
        const int p = g1tab[t];
        e = p & 15; m0 = ((p >> 4) & 255) << 7; n0 = (p >> 12) << 7;
    } else {
        e = e_fixed; m0 = blockIdx.x << 7; n0 = blockIdx.y << 7;
    }
    const int c = ctrl[e];
    if (!TAB && m0 >= c) return;
    const bool frac = e < 4;
    const int HD = frac ? 2048 : 4096;
    const unsigned short* A  = frac ? yb : xb;
    const unsigned short* W1 = wpool + (frac ? W1F_OFF + (size_t)e * 2097152
                                             : W1P_OFF + (size_t)(e - 4) * 4194304);
    const unsigned short* W3 = wpool + (frac ? W3F_OFF + (size_t)e * 2097152
                                             : W3P_OFF + (size_t)(e - 4) * 4194304);
    const int* toks_e = toks + e * NTOK;
    const long long hb = TAB ? (long long)ctrl[10 + e] : 0ll;

    __shared__ __align__(16) unsigned short As[4096], B1s[4096], B3s[4096];
    const int tid = threadIdx.x, lane = tid & 63, w = tid >> 6;
    const int wr = (w >> 1) << 6, wc = (w & 1) << 6;
    const int fr = lane & 15, fq = lane >> 4;

    const unsigned short *pA[2], *pB1[2], *pB3[2];
    unsigned short *lA[2], *lB1[2], *lB3[2];
    #pragma unroll
    for (int i = 0; i < 2; ++i) {
        const int lr = (w << 5) + (i << 4) + (lane >> 2);
        const int lc = (((lane & 3) ^ ((lr >> 1) & 3)) << 3);
        int gr = m0 + lr; if (gr >= c) gr = c - 1;
        const int tok = toks_e[gr];
        pA[i]  = A  + (size_t)tok * DIM + lc;
        pB1[i] = W1 + (size_t)(n0 + lr) * DIM + lc;
        pB3[i] = W3 + (size_t)(n0 + lr) * DIM + lc;
        const int lo = (w << 11) + (i << 10);   // bytes
        lA[i]  = (unsigned short*)((char*)As  + lo);
        lB1[i] = (unsigned short*)((char*)B1s + lo);
        lB3[i] = (unsigned short*)((char*)B3s + lo);
    }

    f32x4 accU[4][4] = {};
    f32x4 accV[4][4] = {};
    for (int k0 = 0; k0 < DIM; k0 += 32) {
        gload16(pA[0]  + k0, lA[0]);  gload16(pA[1]  + k0, lA[1]);
        gload16(pB1[0] + k0, lB1[0]); gload16(pB1[1] + k0, lB1[1]);
        gload16(pB3[0] + k0, lB3[0]); gload16(pB3[1] + k0, lB3[1]);
        __syncthreads();
        short8 af[4], b1f[4], b3f[4];
        #pragma unroll
        for (int i = 0; i < 4; ++i) {
            const int lrA = wr + (i << 4) + fr;
            af[i]  = *(const short8*)(As  + (lrA << 5) + ((fq ^ ((lrA >> 1) & 3)) << 3));
            const int lrB = wc + (i << 4) + fr;
            const int bo  = (lrB << 5) + ((fq ^ ((lrB >> 1) & 3)) << 3);
            b1f[i] = *(const short8*)(B1s + bo);
            b3f[i] = *(const short8*)(B3s + bo);
        }
        #pragma unroll
        for (int mi = 0; mi < 4; ++mi) {
            #pragma unroll
            for (int ni = 0; ni < 4; ++ni) {
                accU[mi][ni] = __builtin_amdgcn_mfma_f32_16x16x32_bf16(af[mi], b1f[ni], accU[mi][ni], 0, 0, 0);
                accV[mi][ni] = __builtin_amdgcn_mfma_f32_16x16x32_bf16(af[mi], b3f[ni], accV[mi][ni], 0, 0, 0);
            }
        }
        __syncthreads();
    }

    #pragma unroll
    for (int mi = 0; mi < 4; ++mi) {
        #pragma unroll
        for (int ni = 0; ni < 4; ++ni) {
            #pragma unroll
            for (int r = 0; r < 4; ++r) {
                const int slot = m0 + wr + mi * 16 + fq * 4 + r;
                if (slot < c) {
                    const int hcol = n0 + wc + ni * 16 + fr;
                    const float uu = accU[mi][ni][r];
                    const float vv = accV[mi][ni][r];
                    const float hv = uu / (1.f + __expf(-uu)) * vv;
                    hpool[hb + (size_t)slot * HD + hcol] = f2b(hv);
                }
            }
        }
    }
}

// ---------------- GEMM2: s = h W2^T; weighted scatter (atomic) ------------
template<bool TAB>
__global__ __launch_bounds__(256, 2) void g2_bf16(
    const int* __restrict__ ctrl, const int* __restrict__ g2tab,
    const unsigned short* __restrict__ hpool, const unsigned short* __restrict__ wpool,
    const int* __restrict__ toks, const float* __restrict__ wl,
    const float* __restrict__ x, const unsigned short* __restrict__ yb,
    const float* __restrict__ rmsw, const float* __restrict__ gam,
    float* __restrict__ out, int e_fixed)
{
    int e, m0, n0;
    if constexpr (TAB) {
        const int t = blockIdx.x;
        if (t >= ctrl[9]) return;
        const int p = g2tab[t];
        e = p & 15; m0 = ((p >> 4) & 255) << 7; n0 = (p >> 12) << 7;
    } else {
        e = e_fixed; m0 = blockIdx.x << 7; n0 = blockIdx.y << 7;
    }
    const int c = ctrl[e];
    if (!TAB && m0 >= c) return;
    const bool frac = e < 4;
    const int K = frac ? 2048 : 4096;
    const int kbeg = TAB ? 0 : (blockIdx.z << 10);
    const int kend = TAB ? K : (kbeg + 1024);
    const unsigned short* Ab = hpool + (TAB ? (long long)ctrl[10 + e] : 0ll);
    const unsigned short* W2 = wpool + (frac ? W2F_OFF + (size_t)e * 2097152
                                             : W2P_OFF + (size_t)(e - 4) * 4194304);
    const int*   toks_e = toks + e * NTOK;
    const float* wl_e   = wl   + e * NTOK;

    __shared__ __align__(16) unsigned short As[4096], Bs[4096];
    const int tid = threadIdx.x, lane = tid & 63, w = tid >> 6;
    const int wr = (w >> 1) << 6, wc = (w & 1) << 6;
    const int fr = lane & 15, fq = lane >> 4;

    const unsigned short *pA[2], *pB[2];
    unsigned short *lA[2], *lB[2];
    #pragma unroll
    for (int i = 0; i < 2; ++i) {
        const int lr = (w << 5) + (i << 4) + (lane >> 2);
        const int lc = (((lane & 3) ^ ((lr >> 1) & 3)) << 3);
        pA[i] = Ab + (size_t)(m0 + lr) * K + lc;
        pB[i] = W2 + (size_t)(n0 + lr) * K + lc;
        const int lo = (w << 11) + (i << 10);
        lA[i] = (unsigned short*)((char*)As + lo);
        lB[i] = (unsigned short*)((char*)Bs + lo);
    }

    f32x4 acc[4][4] = {};
    for (int k0 = kbeg; k0 < kend; k0 += 32) {
        gload16(pA[0] + k0, lA[0]); gload16(pA[1] + k0, lA[1]);
        gload16(pB[0] + k0, lB[0]); gload16(pB[1] + k0, lB[1]);
        __syncthreads();
        short8 af[4], bf[4];
        #pragma unroll
        for (int i = 0; i < 4; ++i) {
            const int lrA = wr + (i << 4) + fr;
            af[i] = *(const short8*)(As + (lrA << 5) + ((fq ^ ((lrA >> 1) & 3)) << 3));
            const int lrB = wc + (i << 4) + fr;
            bf[i] = *(const short8*)(Bs + (lrB << 5) + ((fq ^ ((lrB >> 1) & 3)) << 3));
        }
        #pragma unroll
        for (int mi = 0; mi < 4; ++mi) {
            #pragma unroll
            for (int ni = 0; ni < 4; ++ni)
                acc[mi][ni] = __builtin_amdgcn_mfma_f32_16x16x32_bf16(af[mi], bf[ni], acc[mi][ni], 0, 0, 0);
        }
        __syncthreads();
    }

    #pragma unroll
    for (int mi = 0; mi < 4; ++mi) {
        #pragma unroll
        for (int ni = 0; ni < 4; ++ni) {
            #pragma unroll
            for (int r = 0; r < 4; ++r) {
                const int slot = m0 + wr + mi * 16 + fq * 4 + r;
                if (slot < c) {
                    const int tok  = toks_e[slot];
                    const float wg = wl_e[slot];
                    const int dcol = n0 + wc + ni * 16 + fr;
                    float val = acc[mi][ni][r];
                    if (frac) {
                        const float yv = b2f(yb[(size_t)tok * DIM + dcol]) * rmsw[e * DIM + dcol];
                        val = gam[e * DIM + dcol] * (yv + val) + x[(size_t)tok * DIM + dcol];
                    }
                    atomicAdd(&out[(size_t)tok * DIM + dcol], wg * val);
                }
            }
        }
    }
}

// =============== MICRO fallback (round-1 validated fp32-staging GEMMs) ====
template<int HDIM, bool FRAC>
__global__ __launch_bounds__(256, 2) void g1_f32(
    const unsigned short* __restrict__ Asrc,
    const float* __restrict__ W1, const float* __restrict__ W3,
    const float* __restrict__ rms,
    const int* __restrict__ cntp, const int* __restrict__ toks,
    unsigned short* __restrict__ h)
{
    const int c  = *cntp;
    const int m0 = blockIdx.x * 128;
    if (m0 >= c) return;
    const int n0 = blockIdx.y * 128;
    __shared__ unsigned short As[128][56];
    __shared__ unsigned short B1s[128][56];
    __shared__ unsigned short B3s[128][56];
    const int t = threadIdx.x, lane = t & 63, wv = t >> 6;
    const int wr = (wv >> 1) * 64, wc = (wv & 1) * 64;
    const int fr = lane & 15, fq = lane >> 4;
    const int srow = t >> 1, scol = (t & 1) * 16;
    const int gr = m0 + srow;
    const int atok = (gr < c) ? toks[gr] : 0;
    const unsigned short* aptr = Asrc + (size_t)atok * DIM + scol;
    const float* w1ptr = W1 + (size_t)(n0 + srow) * DIM + scol;
    const float* w3ptr = W3 + (size_t)(n0 + srow) * DIM + scol;
    f32x4 accU[4][4] = {}; f32x4 accV[4][4] = {};
    for (int k0 = 0; k0 < DIM; k0 += 32) {
        short8 a0 = *(const short8*)(aptr + k0);
        short8 a1 = *(const short8*)(aptr + k0 + 8);
        f32x4 u0 = *(const f32x4*)(w1ptr + k0),     u1 = *(const f32x4*)(w1ptr + k0 + 4);
        f32x4 u2 = *(const f32x4*)(w1ptr + k0 + 8), u3 = *(const f32x4*)(w1ptr + k0 + 12);
        f32x4 v0 = *(const f32x4*)(w3ptr + k0),     v1 = *(const f32x4*)(w3ptr + k0 + 4);
        f32x4 v2 = *(const f32x4*)(w3ptr + k0 + 8), v3 = *(const f32x4*)(w3ptr + k0 + 12);
        if constexpr (FRAC) {
            f32x4 r0 = *(const f32x4*)(rms + scol + k0),     r1 = *(const f32x4*)(rms + scol + k0 + 4);
            f32x4 r2 = *(const f32x4*)(rms + scol + k0 + 8), r3 = *(const f32x4*)(rms + scol + k0 + 12);
            u0 *= r0; u1 *= r1; u2 *= r2; u3 *= r3;
            v0 *= r0; v1 *= r1; v2 *= r2; v3 *= r3;
        }
        short8 b1lo = cvt8(u0, u1), b1hi = cvt8(u2, u3);
        short8 b3lo = cvt8(v0, v1), b3hi = cvt8(v2, v3);
        __syncthreads();
        *(short8*)&As[srow][scol] = a0;  *(short8*)&As[srow][scol + 8] = a1;
        *(short8*)&B1s[srow][scol] = b1lo; *(short8*)&B1s[srow][scol + 8] = b1hi;
        *(short8*)&B3s[srow][scol] = b3lo; *(short8*)&B3s[srow][scol + 8] = b3hi;
        __syncthreads();
        short8 af[4], b1f[4], b3f[4];
        #pragma unroll
        for (int i = 0; i < 4; ++i) {
            af[i]  = *(const short8*)&As [wr + i * 16 + fr][fq * 8];
            b1f[i] = *(const short8*)&B1s[wc + i * 16 + fr][fq * 8];
            b3f[i] = *(const short8*)&B3s[wc + i * 16 + fr][fq * 8];
        }
        #pragma unroll
        for (int mi = 0; mi < 4; ++mi)
            #pragma unroll
            for (int ni = 0; ni < 4; ++ni) {
                accU[mi][ni] = __builtin_amdgcn_mfma_f32_16x16x32_bf16(af[mi], b1f[ni], accU[mi][ni], 0, 0, 0);
                accV[mi][ni] = __builtin_amdgcn_mfma_f32_16x16x32_bf16(af[mi], b3f[ni], accV[mi][ni], 0, 0, 0);
            }
    }
    #pragma unroll
    for (int mi = 0; mi < 4; ++mi)
        #pragma unroll
        for (int ni = 0; ni < 4; ++ni)
            #pragma unroll
            for (int r = 0; r < 4; ++r) {
                const int slot = m0 + wr + mi * 16 + fq * 4 + r;
                if (slot < c) {
                    const int hcol = n0 + wc + ni * 16 + fr;
                    const float uu = accU[mi][ni][r], vv = accV[mi][ni][r];
                    h[(size_t)slot * HDIM + hcol] = f2b(uu / (1.f + __expf(-uu)) * vv);
                }
            }
}

template<int K, bool FRAC>
__global__ __launch_bounds__(256, 2) void g2_f32(
    const unsigned short* __restrict__ hsrc, const float* __restrict__ W2,
    const int* __restrict__ cntp, const int* __restrict__ toks,
    const float* __restrict__ wl,
    const float* __restrict__ x, const unsigned short* __restrict__ yb,
    const float* __restrict__ rms, const float* __restrict__ gam,
    float* __restrict__ out)
{
    const int c  = *cntp;
    const int m0 = blockIdx.x * 128;
    if (m0 >= c) return;
    const int n0 = blockIdx.y * 128;
    __shared__ unsigned short As[128][56];
    __shared__ unsigned short Bs[128][56];
    const int t = threadIdx.x, lane = t & 63, wv = t >> 6;
    const int wr = (wv >> 1) * 64, wc = (wv & 1) * 64;
    const int fr = lane & 15, fq = lane >> 4;
    const int srow = t >> 1, scol = (t & 1) * 16;
    const unsigned short* aptr = hsrc + (size_t)(m0 + srow) * K + scol;
    const float* w2ptr = W2 + (size_t)(n0 + srow) * K + scol;
    f32x4 acc[4][4] = {};
    for (int k0 = 0; k0 < K; k0 += 32) {
        short8 a0 = *(const short8*)(aptr + k0);
        short8 a1 = *(const short8*)(aptr + k0 + 8);
        f32x4 u0 = *(const f32x4*)(w2ptr + k0),     u1 = *(const f32x4*)(w2ptr + k0 + 4);
        f32x4 u2 = *(const f32x4*)(w2ptr + k0 + 8), u3 = *(const f32x4*)(w2ptr + k0 + 12);
        short8 blo = cvt8(u0, u1), bhi = cvt8(u2, u3);
        __syncthreads();
        *(short8*)&As[srow][scol] = a0; *(short8*)&As[srow][scol + 8] = a1;
        *(short8*)&Bs[srow][scol] = blo; *(short8*)&Bs[srow][scol + 8] = bhi;
        __syncthreads();
        short8 af[4], bf[4];
        #pragma unroll
        for (int i = 0; i < 4; ++i) {
            af[i] = *(const short8*)&As[wr + i * 16 + fr][fq * 8];
            bf[i] = *(const short8*)&Bs[wc + i * 16 + fr][fq * 8];
        }
        #pragma unroll
        for (int mi = 0; mi < 4; ++mi)
            #pragma unroll
            for (int ni = 0; ni < 4; ++ni)
                acc[mi][ni] = __builtin_amdgcn_mfma_f32_16x16x32_bf16(af[mi], bf[ni], acc[mi][ni], 0, 0, 0);
    }
    #pragma unroll
    for (int mi = 0; mi < 4; ++mi)
        #pragma unroll
        for (int ni = 0; ni < 4; ++ni)
            #pragma unroll
            for (int r = 0; r < 4; ++r) {
                const int slot = m0 + wr + mi * 16 + fq * 4 + r;
                if (slot < c) {
                    const int tok = toks[slot];
                    const float wg = wl[slot];
                    const int dcol = n0 + wc + ni * 16 + fr;
                    float val = acc[mi][ni][r];
                    if constexpr (FRAC) {
                        const float yv = b2f(yb[(size_t)tok * DIM + dcol]) * rms[dcol];
                        val = gam[dcol] * (yv + val) + x[(size_t)tok * DIM + dcol];
                    }
                    out[(size_t)tok * DIM + dcol] += wg * val;
                }
            }
}

// --------------------------------------------------------------------------
extern "C" void kernel_launch(void* const* d_in, const int* in_sizes, int n_in,
                              void* d_out, int out_size, void* d_ws, size_t ws_size,
                              hipStream_t stream)
{
    const float* x    = (const float*)d_in[0];
    const float* Wg   = (const float*)d_in[1];
    const float* rmsw = (const float*)d_in[2];
    const float* gam  = (const float*)d_in[3];
    const float* w1f  = (const float*)d_in[4];
    const float* w3f  = (const float*)d_in[5];
    const float* w2f  = (const float*)d_in[6];
    const float* w1p  = (const float*)d_in[7];
    const float* w3p  = (const float*)d_in[8];
    const float* w2p  = (const float*)d_in[9];
    float* out = (float*)d_out;

    char* ws = (char*)d_ws;
    int*   ctrl  = (int*)ws;
    int*   sel   = (int*)(ws + 1024);
    float* wt    = (float*)(ws + 33792);
    int*   toks  = (int*)(ws + 66560);
    float* wl    = (float*)(ws + 328704);
    int*   g1tab = (int*)(ws + 590848);
    int*   g2tab = (int*)(ws + 608448);
    unsigned short* yb    = (unsigned short*)(ws + 1048576);
    unsigned short* xb    = (unsigned short*)(ws + 17825792);
    unsigned short* wpool = (unsigned short*)(ws + 34603008);
    unsigned short* hpool = (unsigned short*)(ws + 185597952);
    const size_t NEED_FULL  = 326057984ull;
    const size_t NEED_TIGHT = 254787584ull;

    hipMemsetAsync(out, 0, (size_t)out_size * sizeof(float), stream);
    gate_norm  <<<NTOK / 4, 256, 0, stream>>>(x, Wg, sel, wt, yb, xb);
    build_lists<<<8, 256, 0, stream>>>(sel, wt, toks, wl, ctrl);

    if (ws_size >= NEED_TIGHT) {
        cvtw_kernel<<<4096, 256, 0, stream>>>(w1f, w3f, w2f, w1p, w3p, w2p, rmsw, wpool);
        const int mode = (ws_size >= NEED_FULL) ? 0 : 1;
        make_tiles<<<1, 256, 0, stream>>>(ctrl, g1tab, g2tab, mode);
        if (mode == 0) {
            g1_bf16<true><<<4360, 256, 0, stream>>>(ctrl, g1tab, yb, xb, wpool, toks, hpool, 0);
            g2_bf16<true><<<1088, 256, 0, stream>>>(ctrl, g2tab, hpool, wpool, toks, wl,
                                                    x, yb, rmsw, gam, out, 0);
        } else {
            g1_bf16<true><<<2112, 256, 0, stream>>>(ctrl, g1tab, yb, xb, wpool, toks, hpool, 0);
            g2_bf16<true><<<1056, 256, 0, stream>>>(ctrl, g2tab, hpool, wpool, toks, wl,
                                                    x, yb, rmsw, gam, out, 0);
            for (int p = 0; p < 4; ++p) {
                g1_bf16<false><<<dim3(64, 32), 256, 0, stream>>>(ctrl, g1tab, yb, xb, wpool,
                                                                 toks, hpool, 4 + p);
                g2_bf16<false><<<dim3(64, 8, 4), 256, 0, stream>>>(ctrl, g2tab, hpool, wpool,
                                                                   toks, wl, x, yb, rmsw, gam,
                                                                   out, 4 + p);
            }
        }
    } else {
        unsigned short* h = (unsigned short*)(ws + 34603008);   // 67 MB, fits proven budget
        for (int f = 0; f < 4; ++f) {
            g1_f32<2048, true><<<dim3(64, 16), 256, 0, stream>>>(
                yb, w1f + (size_t)f * 2048 * DIM, w3f + (size_t)f * 2048 * DIM,
                rmsw + (size_t)f * DIM, ctrl + f, toks + (size_t)f * NTOK, h);
            g2_f32<2048, true><<<dim3(64, 8), 256, 0, stream>>>(
                h, w2f + (size_t)f * DIM * 2048, ctrl + f, toks + (size_t)f * NTOK,
                wl + (size_t)f * NTOK, x, yb, rmsw + (size_t)f * DIM, gam + (size_t)f * DIM, out);
        }
        for (int p = 0; p < 4; ++p) {
            const int e = 4 + p;
            g1_f32<4096, false><<<dim3(64, 32), 256, 0, stream>>>(
                xb, w1p + (size_t)p * 4096 * DIM, w3p + (size_t)p * 4096 * DIM,
                nullptr, ctrl + e, toks + (size_t)e * NTOK, h);
            g2_f32<4096, false><<<dim3(64, 8), 256, 0, stream>>>(
                h, w2p + (size_t)p * DIM * 4096, ctrl + e, toks + (size_t)e * NTOK,
                wl + (size_t)e * NTOK, nullptr, nullptr, nullptr, nullptr, out);
        }
    }
}